// Round 1
// baseline (1167.440 us; speedup 1.0000x reference)
//
#include <hip/hip_runtime.h>

#define NB 8
#define NC 5
#define NNODE 512
#define FIN 768
#define NH 4
#define DHID 128
#define DOUT 64
#define MT (NB*NNODE)          // 4096 rows (b*512+n)
#define NEG 0.2f

__device__ __forceinline__ float lrelu(float x){ return x > 0.f ? x : NEG*x; }

// ---------------- gather h0 = x[:,0] ----------------
__global__ __launch_bounds__(256) void copy_h0_kernel(const float* __restrict__ x,
                                                      float* __restrict__ h0){
  int tid = blockIdx.x*256 + threadIdx.x;
  const int per_row = FIN/4; // 192 float4 per row
  if (tid >= MT*per_row) return;
  int row = tid / per_row, c4 = tid % per_row;
  int b = row >> 9, n = row & 511;
  const float4* src = (const float4*)(x + (((size_t)b*NC)*NNODE + (size_t)n)*FIN);
  ((float4*)(h0 + (size_t)row*FIN))[c4] = src[c4];
}

// ---------------- fp32 GEMM: O[c] = A[c] @ W[c] ----------------
// A: MT x K (row-major, lda=K), W: K x Nout, O: MT x Nout. 64x64 tile, BK=16.
__global__ __launch_bounds__(256) void gemm_kernel(const float* __restrict__ Ab,
                                                   const float* __restrict__ Wb,
                                                   float* __restrict__ Ob,
                                                   int K, int Nout,
                                                   long a_cs, long w_cs, long o_cs){
  int c = blockIdx.z;
  const float* A = Ab + (size_t)c*a_cs;
  const float* W = Wb + (size_t)c*w_cs;
  float* O = Ob + (size_t)c*o_cs;
  int m0 = blockIdx.y*64, n0 = blockIdx.x*64;
  __shared__ float As[16][64];   // As[k][m]
  __shared__ float Bs[16][64];   // Bs[k][n]
  int t = threadIdx.x;
  int tm = t >> 4, tn = t & 15;
  int arow = m0 + (t >> 2), acol = (t & 3)*4;
  int brow = t >> 4,        bcol = (t & 15)*4;
  float acc[4][4];
  #pragma unroll
  for (int q=0;q<4;q++){ acc[q][0]=0.f; acc[q][1]=0.f; acc[q][2]=0.f; acc[q][3]=0.f; }

  for (int k0 = 0; k0 < K; k0 += 16){
    float4 va = *(const float4*)&A[(size_t)arow*K + k0 + acol];
    float4 vb = *(const float4*)&W[(size_t)(k0 + brow)*Nout + n0 + bcol];
    __syncthreads();
    As[acol+0][t>>2] = va.x;
    As[acol+1][t>>2] = va.y;
    As[acol+2][t>>2] = va.z;
    As[acol+3][t>>2] = va.w;
    *(float4*)&Bs[brow][bcol] = vb;
    __syncthreads();
    #pragma unroll
    for (int k=0;k<16;k++){
      float4 a4 = *(const float4*)&As[k][tm*4];
      float4 b4 = *(const float4*)&Bs[k][tn*4];
      acc[0][0] += a4.x*b4.x; acc[0][1] += a4.x*b4.y; acc[0][2] += a4.x*b4.z; acc[0][3] += a4.x*b4.w;
      acc[1][0] += a4.y*b4.x; acc[1][1] += a4.y*b4.y; acc[1][2] += a4.y*b4.z; acc[1][3] += a4.y*b4.w;
      acc[2][0] += a4.z*b4.x; acc[2][1] += a4.z*b4.y; acc[2][2] += a4.z*b4.z; acc[2][3] += a4.z*b4.w;
      acc[3][0] += a4.w*b4.x; acc[3][1] += a4.w*b4.y; acc[3][2] += a4.w*b4.z; acc[3][3] += a4.w*b4.w;
    }
  }
  #pragma unroll
  for (int q=0;q<4;q++){
    float4 o; o.x=acc[q][0]; o.y=acc[q][1]; o.z=acc[q][2]; o.w=acc[q][3];
    *(float4*)&O[(size_t)(m0+tm*4+q)*Nout + n0 + tn*4] = o;
  }
}

// ---------------- el/er: per (c,row,h) dot(feat_head, a) ----------------
// feat: (NC, MT, NH*D); el/er: (NC, NH, MT)
template<int D>
__global__ __launch_bounds__(256) void eler_kernel(const float* __restrict__ feat,
                                                   const float* __restrict__ al,
                                                   const float* __restrict__ ar,
                                                   float* __restrict__ el,
                                                   float* __restrict__ er){
  int wv = threadIdx.x >> 6, lane = threadIdx.x & 63;
  int task = blockIdx.x*4 + wv;          // (row*NH + h)
  int h = task & 3; int row = task >> 2; // row in [0, NC*MT)
  int c = row >> 12; int m = row & (MT-1);
  const float* f   = feat + (size_t)row*(NH*D) + (size_t)h*D;
  const float* alp = al + ((size_t)c*NH + h)*D;
  const float* arp = ar + ((size_t)c*NH + h)*D;
  float v = f[lane];
  float se = v*alp[lane], sr = v*arp[lane];
  if (D == 128){
    float v1 = f[lane+64];
    se += v1*alp[lane+64]; sr += v1*arp[lane+64];
  }
  #pragma unroll
  for (int o=32;o;o>>=1){ se += __shfl_down(se,o,64); sr += __shfl_down(sr,o,64); }
  if (lane == 0){
    el[((size_t)c*NH + h)*MT + m] = se;
    er[((size_t)c*NH + h)*MT + m] = sr;
  }
}

// ---------------- fused attention aggregation ----------------
// out[c,b,j,h,d] = (1/max(s_j,1e-9)) * sum_i p[i,j]*feat[c,b,i,h,d] + bias[c,h,d]; opt relu
// p[i,j] = adj[b,c,i,j]>0 ? exp(lrelu(el[i]+er[j])) : 0 ; s_j = sum_i p[i,j]
// grid: x=j-tile(8), y=d-tile(D/64), z=c*32+b*4+h
template<int D, int RELU>
__global__ __launch_bounds__(256) void agg_kernel(const float* __restrict__ feat,
                                                  const float* __restrict__ adj,
                                                  const float* __restrict__ el,
                                                  const float* __restrict__ er,
                                                  const float* __restrict__ bias,
                                                  float* __restrict__ outp){
  int z = blockIdx.z; int h = z & 3, b = (z >> 2) & 7, c = z >> 5;
  int j0 = blockIdx.x*64, d0 = blockIdx.y*64;
  const float* adjp = adj + (((size_t)b*NC + c)*NNODE)*NNODE;
  const float* fp   = feat + ((size_t)c*MT + (size_t)b*NNODE)*(NH*D) + (size_t)h*D + d0;
  const float* elp  = el + ((size_t)c*NH + h)*MT + (size_t)b*NNODE;
  const float* erp  = er + ((size_t)c*NH + h)*MT + (size_t)b*NNODE;
  __shared__ float Ps[16][64];  // Ps[i][j]
  __shared__ float Fs[16][64];  // Fs[i][d]
  int t = threadIdx.x;
  int li = t >> 4, lj4 = (t & 15)*4;
  int tj = t >> 4, td = t & 15;
  float4 erj = *(const float4*)&erp[j0 + lj4];
  float acc[4][4];
  float ss[4];
  #pragma unroll
  for (int q=0;q<4;q++){ acc[q][0]=0.f; acc[q][1]=0.f; acc[q][2]=0.f; acc[q][3]=0.f; ss[q]=0.f; }

  for (int i0 = 0; i0 < NNODE; i0 += 16){
    float eli = elp[i0 + li];
    float4 aj = *(const float4*)&adjp[(size_t)(i0+li)*NNODE + j0 + lj4];
    float4 fv = *(const float4*)&fp[(size_t)(i0+li)*(NH*D) + lj4];
    float4 p;
    p.x = aj.x > 0.f ? __expf(lrelu(eli + erj.x)) : 0.f;
    p.y = aj.y > 0.f ? __expf(lrelu(eli + erj.y)) : 0.f;
    p.z = aj.z > 0.f ? __expf(lrelu(eli + erj.z)) : 0.f;
    p.w = aj.w > 0.f ? __expf(lrelu(eli + erj.w)) : 0.f;
    __syncthreads();
    *(float4*)&Ps[li][lj4] = p;
    *(float4*)&Fs[li][lj4] = fv;
    __syncthreads();
    #pragma unroll
    for (int k=0;k<16;k++){
      float4 a4 = *(const float4*)&Ps[k][tj*4];
      float4 b4 = *(const float4*)&Fs[k][td*4];
      acc[0][0] += a4.x*b4.x; acc[0][1] += a4.x*b4.y; acc[0][2] += a4.x*b4.z; acc[0][3] += a4.x*b4.w;
      acc[1][0] += a4.y*b4.x; acc[1][1] += a4.y*b4.y; acc[1][2] += a4.y*b4.z; acc[1][3] += a4.y*b4.w;
      acc[2][0] += a4.z*b4.x; acc[2][1] += a4.z*b4.y; acc[2][2] += a4.z*b4.z; acc[2][3] += a4.z*b4.w;
      acc[3][0] += a4.w*b4.x; acc[3][1] += a4.w*b4.y; acc[3][2] += a4.w*b4.z; acc[3][3] += a4.w*b4.w;
      ss[0] += a4.x; ss[1] += a4.y; ss[2] += a4.z; ss[3] += a4.w;
    }
  }
  float4 bv = *(const float4*)&bias[(size_t)c*(NH*D) + (size_t)h*D + d0 + td*4];
  #pragma unroll
  for (int q=0;q<4;q++){
    float sinv = 1.f / fmaxf(ss[q], 1e-9f);
    float4 o;
    o.x = acc[q][0]*sinv + bv.x;
    o.y = acc[q][1]*sinv + bv.y;
    o.z = acc[q][2]*sinv + bv.z;
    o.w = acc[q][3]*sinv + bv.w;
    if (RELU){
      o.x = fmaxf(o.x, 0.f); o.y = fmaxf(o.y, 0.f);
      o.z = fmaxf(o.z, 0.f); o.w = fmaxf(o.w, 0.f);
    }
    *(float4*)&outp[((size_t)c*MT + (size_t)b*NNODE + j0 + tj*4 + q)*(NH*D) + (size_t)h*D + d0 + td*4] = o;
  }
}

// ---------------- head mean: out[m, c*64+d] = mean_h h2[c,m,h*64+d] ----------------
__global__ __launch_bounds__(256) void mean_kernel(const float* __restrict__ h2,
                                                   float* __restrict__ outp){
  int tid = blockIdx.x*256 + threadIdx.x;
  if (tid >= MT*NC*DOUT) return;
  int d = tid & 63; int r = tid >> 6; int c = r % NC; int m = r / NC;
  const float* p = h2 + ((size_t)c*MT + m)*(NH*DOUT) + d;
  float s = 0.25f*(p[0] + p[DOUT] + p[2*DOUT] + p[3*DOUT]);
  outp[(size_t)m*(NC*DOUT) + (size_t)c*DOUT + d] = s;
}

extern "C" void kernel_launch(void* const* d_in, const int* in_sizes, int n_in,
                              void* d_out, int out_size, void* d_ws, size_t ws_size,
                              hipStream_t stream){
  const float* x  = (const float*)d_in[0];
  const float* adj= (const float*)d_in[1];
  const float* W0 = (const float*)d_in[2];
  const float* al0= (const float*)d_in[3];
  const float* ar0= (const float*)d_in[4];
  const float* b0 = (const float*)d_in[5];
  const float* W1 = (const float*)d_in[6];
  const float* al1= (const float*)d_in[7];
  const float* ar1= (const float*)d_in[8];
  const float* b1 = (const float*)d_in[9];
  const float* W2 = (const float*)d_in[10];
  const float* al2= (const float*)d_in[11];
  const float* ar2= (const float*)d_in[12];
  const float* b2 = (const float*)d_in[13];

  float* ws   = (float*)d_ws;
  float* h0   = ws;                                  // MT*FIN        = 3,145,728
  float* feat = h0   + (size_t)MT*FIN;               // NC*MT*512     = 10,485,760
  float* hbuf = feat + (size_t)NC*MT*512;            // NC*MT*512     = 10,485,760
  float* el   = hbuf + (size_t)NC*MT*512;            // NC*NH*MT      = 81,920
  float* er   = el   + (size_t)NC*NH*MT;             // 81,920  (total ~97.1 MB)

  copy_h0_kernel<<<3072, 256, 0, stream>>>(x, h0);

  // ---- layer 0: h0(768) -> feat(512) ----
  gemm_kernel<<<dim3(8,64,NC), 256, 0, stream>>>(h0, W0, feat, FIN, 512,
                                                 0L, (long)FIN*512, (long)MT*512);
  eler_kernel<128><<<NC*MT*NH/4, 256, 0, stream>>>(feat, al0, ar0, el, er);
  agg_kernel<128,1><<<dim3(8,2,NC*NB*NH), 256, 0, stream>>>(feat, adj, el, er, b0, hbuf);

  // ---- layer 1: hbuf(512) -> feat(512) ----
  gemm_kernel<<<dim3(8,64,NC), 256, 0, stream>>>(hbuf, W1, feat, 512, 512,
                                                 (long)MT*512, (long)512*512, (long)MT*512);
  eler_kernel<128><<<NC*MT*NH/4, 256, 0, stream>>>(feat, al1, ar1, el, er);
  agg_kernel<128,1><<<dim3(8,2,NC*NB*NH), 256, 0, stream>>>(feat, adj, el, er, b1, hbuf);

  // ---- layer 2: hbuf(512) -> feat(256), no relu, then head-mean ----
  gemm_kernel<<<dim3(4,64,NC), 256, 0, stream>>>(hbuf, W2, feat, 512, 256,
                                                 (long)MT*512, (long)512*256, (long)MT*256);
  eler_kernel<64><<<NC*MT*NH/4, 256, 0, stream>>>(feat, al2, ar2, el, er);
  agg_kernel<64,0><<<dim3(8,1,NC*NB*NH), 256, 0, stream>>>(feat, adj, el, er, b2, hbuf);

  mean_kernel<<<5120, 256, 0, stream>>>(hbuf, (float*)d_out);
}

// Round 2
// 444.109 us; speedup vs baseline: 2.6287x; 2.6287x over previous
//
#include <hip/hip_runtime.h>

typedef unsigned int uint;
typedef unsigned short ushort_t;
typedef __attribute__((ext_vector_type(8))) short short8;
typedef __attribute__((ext_vector_type(4))) float f32x4;

#define NB 8
#define NC 5
#define NN 512
#define FIN 768
#define NH 4
#define MT 4096   // NB*NN rows, m = b*512+n

__device__ __forceinline__ float b2f(ushort_t u){ uint x = ((uint)u)<<16; return __builtin_bit_cast(float, x); }
__device__ __forceinline__ ushort_t f2b(float f){
  uint u = __builtin_bit_cast(uint, f);
  u += 0x7FFFu + ((u>>16)&1u);
  return (ushort_t)(u>>16);
}
__device__ __forceinline__ float lrelu(float x){ return x > 0.f ? x : 0.2f*x; }

// async global->LDS, 16B per lane; lds base must be wave-uniform (HW adds lane*16)
#define GLL16(gp, lp) __builtin_amdgcn_global_load_lds( \
    (const __attribute__((address_space(1))) void*)(gp), \
    (__attribute__((address_space(3))) void*)(lp), 16, 0, 0)

// ---------------- h0 = bf16(x[:,0]) ----------------
__global__ __launch_bounds__(256) void conv_h0(const float* __restrict__ x, ushort_t* __restrict__ h0b){
  int tid = blockIdx.x*256 + threadIdx.x;           // over MT*192
  if (tid >= MT*192) return;
  int row = tid/192, q = tid%192;
  int b = row >> 9, n = row & 511;
  float4 v = *(const float4*)(x + ((size_t)(b*NC)*NN + n)*FIN + q*4);
  ushort4 o; o.x = f2b(v.x); o.y = f2b(v.y); o.z = f2b(v.z); o.w = f2b(v.w);
  *(ushort4*)(h0b + (size_t)row*FIN + q*4) = o;
}

// ---------------- Wt[c][n][k] = bf16(W[c][k][n]) ----------------
__global__ __launch_bounds__(256) void wtrans(const float* __restrict__ W, ushort_t* __restrict__ Wt,
                                              int K, int N){
  __shared__ float tile[32][33];
  int c = blockIdx.z;
  int n0 = blockIdx.x*32, k0 = blockIdx.y*32;
  int tx = threadIdx.x & 31, ty = threadIdx.x >> 5;
  const float* Wp = W + (size_t)c*K*N;
  ushort_t* Wtp = Wt + (size_t)c*K*N;
  #pragma unroll
  for (int r=0;r<4;r++) tile[ty+r*8][tx] = Wp[(size_t)(k0+ty+r*8)*N + n0+tx];
  __syncthreads();
  #pragma unroll
  for (int r=0;r<4;r++) Wtp[(size_t)(n0+ty+r*8)*K + k0+tx] = f2b(tile[tx][ty+r*8]);
}

// ---------------- adjT[b*5+c][j][i] = (adj[b][c][i][j]>0) ? bf16(1) : 0 ----------------
__global__ __launch_bounds__(256) void atrans(const float* __restrict__ adj, ushort_t* __restrict__ adjT){
  __shared__ float tile[32][33];
  int z = blockIdx.z;
  int j0 = blockIdx.x*32, i0 = blockIdx.y*32;
  int tx = threadIdx.x & 31, ty = threadIdx.x >> 5;
  const float* ap = adj + (size_t)z*NN*NN;
  ushort_t* op = adjT + (size_t)z*NN*NN;
  #pragma unroll
  for (int r=0;r<4;r++) tile[ty+r*8][tx] = ap[(size_t)(i0+ty+r*8)*NN + j0+tx];
  __syncthreads();
  #pragma unroll
  for (int r=0;r<4;r++) op[(size_t)(j0+ty+r*8)*NN + i0+tx] = (tile[tx][ty+r*8] > 0.f) ? (ushort_t)0x3F80 : (ushort_t)0;
}

// ---------------- MFMA GEMM: featT[c][n][m] = sum_k A[c][m][k]*Wt[c][n][k] ----------------
// A: bf16 [MT][K] row-major; Wt: bf16 [N][K]; out transposed via LDS epilogue.
__global__ __launch_bounds__(256) void gemm_tn(const ushort_t* __restrict__ A,
                                               const ushort_t* __restrict__ Bt,
                                               ushort_t* __restrict__ Ot,
                                               int K, long a_cs, long b_cs, int DT){
  __shared__ __align__(16) char smem[128*136*2];
  ushort_t* As = (ushort_t*)smem;          // [128 m][32 k]
  ushort_t* Bs = As + 128*32;              // [128 n][32 k]
  ushort_t* St = (ushort_t*)smem;          // epilogue [128 n][136]
  int c = blockIdx.z;
  const ushort_t* Ap = A + (size_t)c*a_cs;
  const ushort_t* Bp = Bt + (size_t)c*b_cs;
  int m0 = blockIdx.y*128, n0 = blockIdx.x*128;
  int t = threadIdx.x, lane = t & 63, w = t >> 6;
  int l15 = lane & 15, quad = lane >> 4;
  int wm = (w & 1)*64, wn = (w >> 1)*64;
  f32x4 acc[4][4] = {};
  for (int k0 = 0; k0 < K; k0 += 32){
    __syncthreads();
    {
      int i = t;
      GLL16(Ap + (size_t)(m0 + (i>>2))*K + k0 + (i&3)*8, As + (size_t)(w*64)*8);
      GLL16(Bp + (size_t)(n0 + (i>>2))*K + k0 + (i&3)*8, Bs + (size_t)(w*64)*8);
      i = t + 256;
      GLL16(Ap + (size_t)(m0 + (i>>2))*K + k0 + (i&3)*8, As + (size_t)(w*64 + 256)*8);
      GLL16(Bp + (size_t)(n0 + (i>>2))*K + k0 + (i&3)*8, Bs + (size_t)(w*64 + 256)*8);
    }
    __syncthreads();
    short8 af[4], bfr[4];
    #pragma unroll
    for (int im=0; im<4; im++) af[im] = *(const short8*)(As + (size_t)(wm + im*16 + l15)*32 + quad*8);
    #pragma unroll
    for (int in=0; in<4; in++) bfr[in] = *(const short8*)(Bs + (size_t)(wn + in*16 + l15)*32 + quad*8);
    #pragma unroll
    for (int im=0; im<4; im++)
      #pragma unroll
      for (int in=0; in<4; in++)
        acc[im][in] = __builtin_amdgcn_mfma_f32_16x16x32_bf16(af[im], bfr[in], acc[im][in], 0, 0, 0);
  }
  __syncthreads();
  // C/D layout: col n = lane&15, row m = quad*4+r  -> write transposed tile St[n][m]
  #pragma unroll
  for (int im=0; im<4; im++)
    #pragma unroll
    for (int in=0; in<4; in++){
      int n = wn + in*16 + l15;
      #pragma unroll
      for (int r=0; r<4; r++){
        int m = wm + im*16 + quad*4 + r;
        St[(size_t)n*136 + m] = f2b(acc[im][in][r]);
      }
    }
  __syncthreads();
  int n_loc = t >> 1, half = t & 1;
  const ushort_t* srcp = St + (size_t)n_loc*136 + half*64;
  ushort_t* dst = Ot + (size_t)(c*DT + n0 + n_loc)*MT + m0 + half*64;
  #pragma unroll
  for (int q=0;q<8;q++)
    *(short8*)(dst + q*8) = *(const short8*)(srcp + q*8);
}

// ---------------- el/er from featT ----------------
template<int DH, int DT>
__global__ __launch_bounds__(256) void eler(const ushort_t* __restrict__ featT,
                                            const float* __restrict__ al, const float* __restrict__ ar,
                                            float* __restrict__ el, float* __restrict__ er){
  __shared__ float als[DH], ars[DH];
  int by = blockIdx.y; int c = by>>2, h = by&3;
  int t = threadIdx.x;
  int m = blockIdx.x*256 + t;
  if (t < DH){ als[t] = al[(size_t)(c*NH+h)*DH + t]; ars[t] = ar[(size_t)(c*NH+h)*DH + t]; }
  __syncthreads();
  const ushort_t* fp = featT + (size_t)(c*DT + h*DH)*MT + m;
  float sl = 0.f, sr = 0.f;
  #pragma unroll 8
  for (int d=0; d<DH; d++){
    float f = b2f(fp[(size_t)d*MT]);
    sl += f*als[d]; sr += f*ars[d];
  }
  el[(size_t)(c*NH+h)*MT + m] = sl;
  er[(size_t)(c*NH+h)*MT + m] = sr;
}

// ---------------- fused attention aggregation (MFMA) ----------------
// out[j,d] = (1/max(s_j,1e-9)) * sum_i p[i,j]*feat[i,d] + bias; p generated on the fly.
template<int DH, int DT, int RELU>
__global__ __launch_bounds__(256) void agg(const ushort_t* __restrict__ featT,
                                           const ushort_t* __restrict__ adjT,
                                           const float* __restrict__ el, const float* __restrict__ er,
                                           const float* __restrict__ bias,
                                           ushort_t* __restrict__ outp){
  constexpr int AM = (DH==128) ? 4 : 2;
  __shared__ __align__(16) ushort_t Ps[128*32];   // [j][i]
  __shared__ __align__(16) ushort_t Fs[DH*32];    // [d][i]
  __shared__ float el_s[512];
  __shared__ float sred[256];
  __shared__ float sinv_s[128];
  int z = blockIdx.z; int c = z>>5, b = (z>>2)&7, h = z&3;
  int j0 = blockIdx.x*128;
  int t = threadIdx.x, lane = t&63, w = t>>6, l15 = lane&15, quad = lane>>4;
  int wm = (DH==128) ? (w&1)*64 : w*32;
  int wn = (DH==128) ? (w>>1)*64 : 0;
  const ushort_t* fT = featT + (size_t)(c*DT + h*DH)*MT + b*NN;
  const ushort_t* aT = adjT + ((size_t)(b*NC + c)*NN + j0)*NN;
  const float* elp = el + (size_t)(c*NH + h)*MT + b*NN;
  el_s[t] = elp[t]; el_s[t+256] = elp[t+256];
  float er_t = er[(size_t)(c*NH+h)*MT + b*NN + j0 + (t&127)];
  int jj = t & 127, chb = t >> 7;
  f32x4 acc[AM][4] = {};
  float ss = 0.f;
  __syncthreads();
  for (int i0 = 0; i0 < NN; i0 += 32){
    // stage F (async) ...
    {
      int i = t;
      GLL16(fT + (size_t)(i>>2)*MT + i0 + (i&3)*8, Fs + (size_t)(w*64)*8);
      if (DH == 128){
        i = t + 256;
        GLL16(fT + (size_t)(i>>2)*MT + i0 + (i&3)*8, Fs + (size_t)(w*64 + 256)*8);
      }
    }
    // ... overlap with P generation (chunks chb and chb+2, fixed j=jj)
    #pragma unroll
    for (int cc=0; cc<2; cc++){
      int ch = chb + cc*2;
      int ib = i0 + ch*8;
      uint4 av = *(const uint4*)(aT + (size_t)jj*NN + ib);
      float4 ea = *(const float4*)&el_s[ib];
      float4 eb = *(const float4*)&el_s[ib+4];
      float ev[8] = {ea.x, ea.y, ea.z, ea.w, eb.x, eb.y, eb.z, eb.w};
      uint mw[4] = {av.x, av.y, av.z, av.w};
      short8 pp;
      #pragma unroll
      for (int q=0;q<8;q++){
        ushort_t mk = (ushort_t)(mw[q>>1] >> ((q&1)*16));
        float e = ev[q] + er_t;
        float p = mk ? __expf(lrelu(e)) : 0.f;
        ushort_t ub = f2b(p);
        pp[q] = (short)ub;
        ss += b2f(ub);          // denominator consistent with bf16 numerator
      }
      *(short8*)(Ps + (size_t)jj*32 + ch*8) = pp;
    }
    __syncthreads();
    short8 af[AM], bfr[4];
    #pragma unroll
    for (int im=0; im<AM; im++) af[im] = *(const short8*)(Ps + (size_t)(wm + im*16 + l15)*32 + quad*8);
    #pragma unroll
    for (int in=0; in<4; in++) bfr[in] = *(const short8*)(Fs + (size_t)(wn + in*16 + l15)*32 + quad*8);
    #pragma unroll
    for (int im=0; im<AM; im++)
      #pragma unroll
      for (int in=0; in<4; in++)
        acc[im][in] = __builtin_amdgcn_mfma_f32_16x16x32_bf16(af[im], bfr[in], acc[im][in], 0, 0, 0);
    __syncthreads();
  }
  sred[t] = ss;
  __syncthreads();
  if (t < 128) sinv_s[t] = 1.f / fmaxf(sred[t] + sred[t+128], 1e-9f);
  __syncthreads();
  ushort_t* op = outp + ((size_t)c*MT + b*NN + j0)*DT + h*DH;
  #pragma unroll
  for (int in=0; in<4; in++){
    int dn = wn + in*16 + l15;
    float bv = bias[(size_t)c*DT + h*DH + dn];
    #pragma unroll
    for (int im=0; im<AM; im++){
      #pragma unroll
      for (int r=0; r<4; r++){
        int jr = wm + im*16 + quad*4 + r;
        float o = acc[im][in][r]*sinv_s[jr] + bv;
        if (RELU) o = fmaxf(o, 0.f);
        op[(size_t)jr*DT + dn] = f2b(o);
      }
    }
  }
}

// ---------------- head mean ----------------
__global__ __launch_bounds__(256) void meank(const ushort_t* __restrict__ h2, float* __restrict__ outp){
  int tid = blockIdx.x*256 + threadIdx.x;
  if (tid >= MT*NC*64) return;
  int d = tid & 63; int r = tid >> 6; int c = r % NC; int m = r / NC;
  const ushort_t* p = h2 + ((size_t)c*MT + m)*256 + d;
  float s = 0.25f*(b2f(p[0]) + b2f(p[64]) + b2f(p[128]) + b2f(p[192]));
  outp[(size_t)m*(NC*64) + c*64 + d] = s;
}

extern "C" void kernel_launch(void* const* d_in, const int* in_sizes, int n_in,
                              void* d_out, int out_size, void* d_ws, size_t ws_size,
                              hipStream_t stream){
  const float* x   = (const float*)d_in[0];
  const float* adj = (const float*)d_in[1];
  const float* W0  = (const float*)d_in[2];
  const float* al0 = (const float*)d_in[3];
  const float* ar0 = (const float*)d_in[4];
  const float* b0  = (const float*)d_in[5];
  const float* W1  = (const float*)d_in[6];
  const float* al1 = (const float*)d_in[7];
  const float* ar1 = (const float*)d_in[8];
  const float* b1  = (const float*)d_in[9];
  const float* W2  = (const float*)d_in[10];
  const float* al2 = (const float*)d_in[11];
  const float* ar2 = (const float*)d_in[12];
  const float* b2  = (const float*)d_in[13];

  ushort_t* h0b  = (ushort_t*)d_ws;                 // MT*768
  ushort_t* Wt0  = h0b  + (size_t)MT*FIN;           // 5*512*768
  ushort_t* Wt1  = Wt0  + (size_t)5*512*768;        // 5*512*512
  ushort_t* Wt2  = Wt1  + (size_t)5*512*512;        // 5*256*512
  ushort_t* adjT = Wt2  + (size_t)5*256*512;        // 40*512*512
  ushort_t* featT= adjT + (size_t)40*512*512;       // 5*512*4096
  ushort_t* hnat = featT+ (size_t)5*512*4096;       // 5*4096*512
  float*    elp  = (float*)(hnat + (size_t)5*4096*512);  // 5*4*4096
  float*    erp  = elp + (size_t)NC*NH*MT;

  conv_h0<<<3072, 256, 0, stream>>>(x, h0b);
  wtrans<<<dim3(16, 24, 5), 256, 0, stream>>>(W0, Wt0, 768, 512);
  wtrans<<<dim3(16, 16, 5), 256, 0, stream>>>(W1, Wt1, 512, 512);
  wtrans<<<dim3(8, 16, 5), 256, 0, stream>>>(W2, Wt2, 512, 256);
  atrans<<<dim3(16, 16, 40), 256, 0, stream>>>(adj, adjT);

  // layer 0
  gemm_tn<<<dim3(4, 32, 5), 256, 0, stream>>>(h0b, Wt0, featT, 768, 0L, (long)512*768, 512);
  eler<128,512><<<dim3(16, 20), 256, 0, stream>>>(featT, al0, ar0, elp, erp);
  agg<128,512,1><<<dim3(4, 1, 160), 256, 0, stream>>>(featT, adjT, elp, erp, b0, hnat);
  // layer 1
  gemm_tn<<<dim3(4, 32, 5), 256, 0, stream>>>(hnat, Wt1, featT, 512, (long)MT*512, (long)512*512, 512);
  eler<128,512><<<dim3(16, 20), 256, 0, stream>>>(featT, al1, ar1, elp, erp);
  agg<128,512,1><<<dim3(4, 1, 160), 256, 0, stream>>>(featT, adjT, elp, erp, b1, hnat);
  // layer 2 (no relu)
  gemm_tn<<<dim3(2, 32, 5), 256, 0, stream>>>(hnat, Wt2, featT, 512, (long)MT*512, (long)256*512, 256);
  eler<64,256><<<dim3(16, 20), 256, 0, stream>>>(featT, al2, ar2, elp, erp);
  agg<64,256,0><<<dim3(4, 1, 160), 256, 0, stream>>>(featT, adjT, elp, erp, b2, hnat);

  meank<<<5120, 256, 0, stream>>>(hnat, (float*)d_out);
}

// Round 3
// 380.796 us; speedup vs baseline: 3.0658x; 1.1663x over previous
//
#include <hip/hip_runtime.h>

typedef unsigned int uint;
typedef unsigned short ushort_t;
typedef __attribute__((ext_vector_type(8))) short short8;
typedef __attribute__((ext_vector_type(4))) float f32x4;

#define NB 8
#define NC 5
#define NN 512
#define FIN 768
#define NH 4
#define MT 4096   // NB*NN rows, m = b*512+n

__device__ __forceinline__ float b2f(ushort_t u){ uint x = ((uint)u)<<16; return __builtin_bit_cast(float, x); }
__device__ __forceinline__ ushort_t f2b(float f){
  uint u = __builtin_bit_cast(uint, f);
  u += 0x7FFFu + ((u>>16)&1u);
  return (ushort_t)(u>>16);
}

// async global->LDS, 16B per lane; lds base must be wave-uniform (HW adds lane*16)
#define GLL16(gp, lp) __builtin_amdgcn_global_load_lds( \
    (const __attribute__((address_space(1))) void*)(gp), \
    (__attribute__((address_space(3))) void*)(lp), 16, 0, 0)

// ---------------- h0 = bf16(x[:,0]) ----------------
__global__ __launch_bounds__(256) void conv_h0(const float* __restrict__ x, ushort_t* __restrict__ h0b){
  int tid = blockIdx.x*256 + threadIdx.x;           // over MT*192
  if (tid >= MT*192) return;
  int row = tid/192, q = tid%192;
  int b = row >> 9, n = row & 511;
  float4 v = *(const float4*)(x + ((size_t)(b*NC)*NN + n)*FIN + q*4);
  ushort4 o; o.x = f2b(v.x); o.y = f2b(v.y); o.z = f2b(v.z); o.w = f2b(v.w);
  *(ushort4*)(h0b + (size_t)row*FIN + q*4) = o;
}

// ---------------- Wt[c][n][k] = bf16(W[c][k][n]) ----------------
__global__ __launch_bounds__(256) void wtrans(const float* __restrict__ W, ushort_t* __restrict__ Wt,
                                              int K, int N){
  __shared__ float tile[32][33];
  int c = blockIdx.z;
  int n0 = blockIdx.x*32, k0 = blockIdx.y*32;
  int tx = threadIdx.x & 31, ty = threadIdx.x >> 5;
  const float* Wp = W + (size_t)c*K*N;
  ushort_t* Wtp = Wt + (size_t)c*K*N;
  #pragma unroll
  for (int r=0;r<4;r++) tile[ty+r*8][tx] = Wp[(size_t)(k0+ty+r*8)*N + n0+tx];
  __syncthreads();
  #pragma unroll
  for (int r=0;r<4;r++) Wtp[(size_t)(n0+ty+r*8)*K + k0+tx] = f2b(tile[tx][ty+r*8]);
}

// ---------------- adjacency bit-pack: adjB[zz][iw][j], bit q = adj[b][c][iw*32+q][j]>0 ----------------
// zz = b*NC+c; iw = i/32 (16 words); j in [0,512)
__global__ __launch_bounds__(256) void abits_kernel(const float* __restrict__ adj, uint* __restrict__ adjB){
  int zz = blockIdx.y, iw = blockIdx.x;
  int t = threadIdx.x;
  const float* ap = adj + (size_t)zz*NN*NN + (size_t)iw*32*NN;
  uint w0 = 0, w1 = 0;
  #pragma unroll 8
  for (int q=0;q<32;q++){
    if (ap[(size_t)q*NN + t]       > 0.f) w0 |= (1u<<q);
    if (ap[(size_t)q*NN + t + 256] > 0.f) w1 |= (1u<<q);
  }
  adjB[((size_t)zz*16 + iw)*512 + t]       = w0;
  adjB[((size_t)zz*16 + iw)*512 + t + 256] = w1;
}

// ---------------- MFMA GEMM: featT[c][n][m] = sum_k A[c][m][k]*Wt[c][n][k] ----------------
__global__ __launch_bounds__(256) void gemm_tn(const ushort_t* __restrict__ A,
                                               const ushort_t* __restrict__ Bt,
                                               ushort_t* __restrict__ Ot,
                                               int K, long a_cs, long b_cs, int DT){
  __shared__ __align__(16) char smem[128*136*2];
  ushort_t* As = (ushort_t*)smem;          // [128 m][32 k]
  ushort_t* Bs = As + 128*32;              // [128 n][32 k]
  ushort_t* St = (ushort_t*)smem;          // epilogue [128 n][136]
  int c = blockIdx.z;
  const ushort_t* Ap = A + (size_t)c*a_cs;
  const ushort_t* Bp = Bt + (size_t)c*b_cs;
  int m0 = blockIdx.y*128, n0 = blockIdx.x*128;
  int t = threadIdx.x, lane = t & 63, w = t >> 6;
  int l15 = lane & 15, quad = lane >> 4;
  int wm = (w & 1)*64, wn = (w >> 1)*64;
  f32x4 acc[4][4] = {};
  for (int k0 = 0; k0 < K; k0 += 32){
    __syncthreads();
    {
      int i = t;
      GLL16(Ap + (size_t)(m0 + (i>>2))*K + k0 + (i&3)*8, As + (size_t)(w*64)*8);
      GLL16(Bp + (size_t)(n0 + (i>>2))*K + k0 + (i&3)*8, Bs + (size_t)(w*64)*8);
      i = t + 256;
      GLL16(Ap + (size_t)(m0 + (i>>2))*K + k0 + (i&3)*8, As + (size_t)(w*64 + 256)*8);
      GLL16(Bp + (size_t)(n0 + (i>>2))*K + k0 + (i&3)*8, Bs + (size_t)(w*64 + 256)*8);
    }
    __syncthreads();
    short8 af[4], bfr[4];
    #pragma unroll
    for (int im=0; im<4; im++) af[im] = *(const short8*)(As + (size_t)(wm + im*16 + l15)*32 + quad*8);
    #pragma unroll
    for (int in=0; in<4; in++) bfr[in] = *(const short8*)(Bs + (size_t)(wn + in*16 + l15)*32 + quad*8);
    #pragma unroll
    for (int im=0; im<4; im++)
      #pragma unroll
      for (int in=0; in<4; in++)
        acc[im][in] = __builtin_amdgcn_mfma_f32_16x16x32_bf16(af[im], bfr[in], acc[im][in], 0, 0, 0);
  }
  __syncthreads();
  #pragma unroll
  for (int im=0; im<4; im++)
    #pragma unroll
    for (int in=0; in<4; in++){
      int n = wn + in*16 + l15;
      #pragma unroll
      for (int r=0; r<4; r++){
        int m = wm + im*16 + quad*4 + r;
        St[(size_t)n*136 + m] = f2b(acc[im][in][r]);
      }
    }
  __syncthreads();
  int n_loc = t >> 1, half = t & 1;
  const ushort_t* srcp = St + (size_t)n_loc*136 + half*64;
  ushort_t* dst = Ot + (size_t)(c*DT + n0 + n_loc)*MT + m0 + half*64;
  #pragma unroll
  for (int q=0;q<8;q++)
    *(short8*)(dst + q*8) = *(const short8*)(srcp + q*8);
}

// ---------------- el/er + separable exps from featT ----------------
// el,er,E1=exp(el),E2=exp(0.2*el),R1=exp(er),R2=exp(0.2*er), all [c][h][m] fp32
template<int DH, int DT>
__global__ __launch_bounds__(256) void eler(const ushort_t* __restrict__ featT,
                                            const float* __restrict__ al, const float* __restrict__ ar,
                                            float* __restrict__ el, float* __restrict__ er,
                                            float* __restrict__ E1, float* __restrict__ E2,
                                            float* __restrict__ R1, float* __restrict__ R2){
  __shared__ float als[DH], ars[DH];
  int by = blockIdx.y; int c = by>>2, h = by&3;
  int t = threadIdx.x;
  int m = blockIdx.x*256 + t;
  if (t < DH){ als[t] = al[(size_t)(c*NH+h)*DH + t]; ars[t] = ar[(size_t)(c*NH+h)*DH + t]; }
  __syncthreads();
  const ushort_t* fp = featT + (size_t)(c*DT + h*DH)*MT + m;
  float sl = 0.f, sr = 0.f;
  #pragma unroll 8
  for (int d=0; d<DH; d++){
    float f = b2f(fp[(size_t)d*MT]);
    sl += f*als[d]; sr += f*ars[d];
  }
  size_t idx = (size_t)(c*NH+h)*MT + m;
  el[idx] = sl; er[idx] = sr;
  E1[idx] = __expf(sl); E2[idx] = __expf(0.2f*sl);
  R1[idx] = __expf(sr); R2[idx] = __expf(0.2f*sr);
}

// ---------------- fused attention aggregation (MFMA) ----------------
// out[j,d] = (1/max(s_j,1e-9)) * sum_i p[i,j]*feat[i,d] + bias
// p[i,j] = mask * ((el_i+er_j>0) ? E1_i*R1_j : E2_i*R2_j)   (no exp in loop)
// grid: x = j-tile (8 x 64j), z = c*32+b*4+h (160). Block tile: M=64(j) x N=DH.
template<int DH, int DT, int RELU>
__global__ __launch_bounds__(256) void agg(const ushort_t* __restrict__ featT,
                                           const uint* __restrict__ adjB,
                                           const float* __restrict__ el, const float* __restrict__ er,
                                           const float* __restrict__ E1, const float* __restrict__ E2,
                                           const float* __restrict__ R1, const float* __restrict__ R2,
                                           const float* __restrict__ bias,
                                           ushort_t* __restrict__ outp){
  constexpr int BN = DH/32;                       // 4 or 2 B-frags per wave
  __shared__ __align__(16) ushort_t Ps[64*40];    // [j][32 i + 8 pad]
  __shared__ __align__(16) ushort_t Fs[DH*32];    // [d][32 i]
  __shared__ uint  Ms[16*64];                     // [iw][j]
  __shared__ float el_s[512], E1_s[512], E2_s[512];
  __shared__ float sred[256];
  __shared__ float sinv_s[64];
  int z = blockIdx.z; int c = z>>5, b = (z>>2)&7, h = z&3;
  int zz = b*NC + c;
  int j0 = blockIdx.x*64;
  int t = threadIdx.x, lane = t&63, w = t>>6, l15 = lane&15, quad = lane>>4;
  int wm = (w&1)*32, wn = (w>>1)*(DH/2);
  int jj = t & 63, ch = t >> 6;                   // P-gen: thread owns (j=jj, 8-i chunk ch)
  const ushort_t* fT = featT + (size_t)(c*DT + h*DH)*MT + b*NN;
  size_t eb = (size_t)(c*NH + h)*MT + b*NN;
  // prologue: stage per-node arrays + adjacency bits
  el_s[t] = el[eb + t];  el_s[t+256] = el[eb + t+256];
  E1_s[t] = E1[eb + t];  E1_s[t+256] = E1[eb + t+256];
  E2_s[t] = E2[eb + t];  E2_s[t+256] = E2[eb + t+256];
  #pragma unroll
  for (int k=0;k<4;k++){
    int idx = k*256 + t;                          // [iw][j'] with iw=idx>>6, j'=idx&63
    Ms[idx] = adjB[((size_t)zz*16 + (idx>>6))*512 + j0 + (idx&63)];
  }
  float er_t = er[eb + j0 + jj];
  float R1_t = R1[eb + j0 + jj];
  float R2_t = R2[eb + j0 + jj];
  f32x4 acc[2][BN] = {};
  float ss = 0.f;
  for (int i0 = 0; i0 < NN; i0 += 32){
    __syncthreads();
    // stage F tile (DH x 32) async
    {
      int i = t;
      GLL16(fT + (size_t)(i>>2)*MT + i0 + (i&3)*8, Fs + (size_t)(w*64)*8);
      if (DH == 128){
        i = t + 256;
        GLL16(fT + (size_t)(i>>2)*MT + i0 + (i&3)*8, Fs + (size_t)(256 + w*64)*8);
      }
    }
    // P-gen: 8 entries, branch-free, no exp
    {
      uint mbyte = (Ms[(i0>>5)*64 + jj] >> (ch*8)) & 0xFFu;
      int ib = i0 + ch*8;
      short8 pp;
      #pragma unroll
      for (int q=0;q<8;q++){
        float s  = el_s[ib+q] + er_t;
        float p1 = E1_s[ib+q]*R1_t;
        float p2 = E2_s[ib+q]*R2_t;
        float p  = ((mbyte>>q)&1u) ? (s > 0.f ? p1 : p2) : 0.f;
        ushort_t ub = f2b(p);
        pp[q] = (short)ub;
        ss += b2f(ub);                            // denominator consistent with bf16 numerator
      }
      *(short8*)(Ps + (size_t)jj*40 + ch*8) = pp;
    }
    __syncthreads();
    short8 af[2], bfr[BN];
    #pragma unroll
    for (int im=0; im<2; im++) af[im] = *(const short8*)(Ps + (size_t)(wm + im*16 + l15)*40 + quad*8);
    #pragma unroll
    for (int in=0; in<BN; in++) bfr[in] = *(const short8*)(Fs + (size_t)(wn + in*16 + l15)*32 + quad*8);
    #pragma unroll
    for (int im=0; im<2; im++)
      #pragma unroll
      for (int in=0; in<BN; in++)
        acc[im][in] = __builtin_amdgcn_mfma_f32_16x16x32_bf16(af[im], bfr[in], acc[im][in], 0, 0, 0);
  }
  __syncthreads();
  sred[t] = ss;
  __syncthreads();
  if (t < 64) sinv_s[t] = 1.f / fmaxf(sred[t] + sred[t+64] + sred[t+128] + sred[t+192], 1e-9f);
  __syncthreads();
  ushort_t* op = outp + ((size_t)c*MT + b*NN + j0)*DT + h*DH;
  #pragma unroll
  for (int in=0; in<BN; in++){
    int dn = wn + in*16 + l15;
    float bv = bias[(size_t)c*DT + h*DH + dn];
    #pragma unroll
    for (int im=0; im<2; im++){
      #pragma unroll
      for (int r=0; r<4; r++){
        int jr = wm + im*16 + quad*4 + r;
        float o = acc[im][in][r]*sinv_s[jr] + bv;
        if (RELU) o = fmaxf(o, 0.f);
        op[(size_t)jr*DT + dn] = f2b(o);
      }
    }
  }
}

// ---------------- head mean ----------------
__global__ __launch_bounds__(256) void meank(const ushort_t* __restrict__ h2, float* __restrict__ outp){
  int tid = blockIdx.x*256 + threadIdx.x;
  if (tid >= MT*NC*64) return;
  int d = tid & 63; int r = tid >> 6; int c = r % NC; int m = r / NC;
  const ushort_t* p = h2 + ((size_t)c*MT + m)*256 + d;
  float s = 0.25f*(b2f(p[0]) + b2f(p[64]) + b2f(p[128]) + b2f(p[192]));
  outp[(size_t)m*(NC*64) + c*64 + d] = s;
}

extern "C" void kernel_launch(void* const* d_in, const int* in_sizes, int n_in,
                              void* d_out, int out_size, void* d_ws, size_t ws_size,
                              hipStream_t stream){
  const float* x   = (const float*)d_in[0];
  const float* adj = (const float*)d_in[1];
  const float* W0  = (const float*)d_in[2];
  const float* al0 = (const float*)d_in[3];
  const float* ar0 = (const float*)d_in[4];
  const float* b0  = (const float*)d_in[5];
  const float* W1  = (const float*)d_in[6];
  const float* al1 = (const float*)d_in[7];
  const float* ar1 = (const float*)d_in[8];
  const float* b1  = (const float*)d_in[9];
  const float* W2  = (const float*)d_in[10];
  const float* al2 = (const float*)d_in[11];
  const float* ar2 = (const float*)d_in[12];
  const float* b2  = (const float*)d_in[13];

  ushort_t* h0b  = (ushort_t*)d_ws;                 // MT*768
  ushort_t* Wt0  = h0b  + (size_t)MT*FIN;           // 5*512*768
  ushort_t* Wt1  = Wt0  + (size_t)5*512*768;        // 5*512*512
  ushort_t* Wt2  = Wt1  + (size_t)5*512*512;        // 5*256*512
  ushort_t* featT= Wt2  + (size_t)5*256*512;        // 5*512*4096
  ushort_t* hnat = featT+ (size_t)5*512*4096;       // 5*4096*512
  uint*     adjB = (uint*)(hnat + (size_t)5*4096*512);   // 40*16*512 uints
  float*    elp  = (float*)(adjB + (size_t)40*16*512);
  float*    erp  = elp + (size_t)NC*NH*MT;
  float*    E1p  = erp + (size_t)NC*NH*MT;
  float*    E2p  = E1p + (size_t)NC*NH*MT;
  float*    R1p  = E2p + (size_t)NC*NH*MT;
  float*    R2p  = R1p + (size_t)NC*NH*MT;

  conv_h0<<<3072, 256, 0, stream>>>(x, h0b);
  wtrans<<<dim3(16, 24, 5), 256, 0, stream>>>(W0, Wt0, 768, 512);
  wtrans<<<dim3(16, 16, 5), 256, 0, stream>>>(W1, Wt1, 512, 512);
  wtrans<<<dim3(8, 16, 5), 256, 0, stream>>>(W2, Wt2, 512, 256);
  abits_kernel<<<dim3(16, 40), 256, 0, stream>>>(adj, adjB);

  // layer 0
  gemm_tn<<<dim3(4, 32, 5), 256, 0, stream>>>(h0b, Wt0, featT, 768, 0L, (long)512*768, 512);
  eler<128,512><<<dim3(16, 20), 256, 0, stream>>>(featT, al0, ar0, elp, erp, E1p, E2p, R1p, R2p);
  agg<128,512,1><<<dim3(8, 1, 160), 256, 0, stream>>>(featT, adjB, elp, erp, E1p, E2p, R1p, R2p, b0, hnat);
  // layer 1
  gemm_tn<<<dim3(4, 32, 5), 256, 0, stream>>>(hnat, Wt1, featT, 512, (long)MT*512, (long)512*512, 512);
  eler<128,512><<<dim3(16, 20), 256, 0, stream>>>(featT, al1, ar1, elp, erp, E1p, E2p, R1p, R2p);
  agg<128,512,1><<<dim3(8, 1, 160), 256, 0, stream>>>(featT, adjB, elp, erp, E1p, E2p, R1p, R2p, b1, hnat);
  // layer 2 (no relu)
  gemm_tn<<<dim3(2, 32, 5), 256, 0, stream>>>(hnat, Wt2, featT, 512, (long)MT*512, (long)256*512, 256);
  eler<64,256><<<dim3(16, 20), 256, 0, stream>>>(featT, al2, ar2, elp, erp, E1p, E2p, R1p, R2p);
  agg<64,256,0><<<dim3(8, 1, 160), 256, 0, stream>>>(featT, adjB, elp, erp, E1p, E2p, R1p, R2p, b2, hnat);

  meank<<<5120, 256, 0, stream>>>(hnat, (float*)d_out);
}

// Round 4
// 314.381 us; speedup vs baseline: 3.7135x; 1.2113x over previous
//
#include <hip/hip_runtime.h>

typedef unsigned int uint;
typedef unsigned short ushort_t;
typedef __attribute__((ext_vector_type(8))) short short8;
typedef __attribute__((ext_vector_type(4))) float f32x4;

#define NB 8
#define NC 5
#define NN 512
#define FIN 768
#define NH 4
#define MT 4096   // NB*NN rows, m = b*512+n
#define LOG2E 1.4426950408889634f

#if __has_builtin(__builtin_amdgcn_exp2f)
#define EXP2F(v) __builtin_amdgcn_exp2f(v)
#else
#define EXP2F(v) __expf((v)*0.6931471805599453f)
#endif

__device__ __forceinline__ float b2f(ushort_t u){ uint x = ((uint)u)<<16; return __builtin_bit_cast(float, x); }
__device__ __forceinline__ ushort_t f2b(float f){
  uint u = __builtin_bit_cast(uint, f);
  u += 0x7FFFu + ((u>>16)&1u);
  return (ushort_t)(u>>16);
}
__device__ __forceinline__ ushort_t f2b_fast(float f){
  uint u = __builtin_bit_cast(uint, f);
  return (ushort_t)((u + 0x8000u)>>16);
}

// async global->LDS, 16B/lane; lds base wave-uniform (HW adds lane*16), global addr per-lane
#define GLL16(gp, lp) __builtin_amdgcn_global_load_lds( \
    (const __attribute__((address_space(1))) void*)(gp), \
    (__attribute__((address_space(3))) void*)(lp), 16, 0, 0)

// ================ fused prep: conv_h0 | wtrans x3 | adjacency bitpack ================
__global__ __launch_bounds__(256) void prep(const float* __restrict__ x, ushort_t* __restrict__ h0b,
                                            const float* __restrict__ W0, ushort_t* __restrict__ Wt0,
                                            const float* __restrict__ W1, ushort_t* __restrict__ Wt1,
                                            const float* __restrict__ W2, ushort_t* __restrict__ Wt2,
                                            const float* __restrict__ adj, uint* __restrict__ adjB){
  __shared__ float tile[32][33];
  int bid = blockIdx.x, t = threadIdx.x;
  if (bid < 3072){
    int tid = bid*256 + t;                    // over MT*192
    int row = tid/192, q = tid%192;
    int b = row >> 9, n = row & 511;
    float4 v = *(const float4*)(x + ((size_t)(b*NC)*NN + n)*FIN + q*4);
    ushort4 o; o.x = f2b(v.x); o.y = f2b(v.y); o.z = f2b(v.z); o.w = f2b(v.w);
    *(ushort4*)(h0b + (size_t)row*FIN + q*4) = o;
  } else if (bid < 6912){
    const float* W; ushort_t* Wt; int K, N, c, x0, y0;
    if (bid < 4992){ int l = bid-3072; K=768; N=512; W=W0; Wt=Wt0; c=l/384; int r=l%384; x0=r%16; y0=r/16; }
    else if (bid < 6272){ int l = bid-4992; K=512; N=512; W=W1; Wt=Wt1; c=l/256; int r=l%256; x0=r%16; y0=r/16; }
    else { int l = bid-6272; K=512; N=256; W=W2; Wt=Wt2; c=l/128; int r=l%128; x0=r%8; y0=r/8; }
    int n0 = x0*32, k0 = y0*32;
    int tx = t & 31, ty = t >> 5;
    const float* Wp = W + (size_t)c*K*N;
    ushort_t* Wtp = Wt + (size_t)c*K*N;
    #pragma unroll
    for (int r=0;r<4;r++) tile[ty+r*8][tx] = Wp[(size_t)(k0+ty+r*8)*N + n0+tx];
    __syncthreads();
    #pragma unroll
    for (int r=0;r<4;r++) Wtp[(size_t)(n0+ty+r*8)*K + k0+tx] = f2b(tile[tx][ty+r*8]);
  } else {
    int l = bid - 6912;                       // 640: zz*16 + iw
    int iw = l & 15, zz = l >> 4;
    const float* ap = adj + (size_t)zz*NN*NN + (size_t)iw*32*NN;
    uint w0 = 0, w1 = 0;
    #pragma unroll 8
    for (int q=0;q<32;q++){
      if (ap[(size_t)q*NN + t]       > 0.f) w0 |= (1u<<q);
      if (ap[(size_t)q*NN + t + 256] > 0.f) w1 |= (1u<<q);
    }
    adjB[((size_t)zz*16 + iw)*512 + t]       = w0;
    adjB[((size_t)zz*16 + iw)*512 + t + 256] = w1;
  }
}

// ================ MFMA GEMM: featB[c][m/8][n][8] = (A @ Wt^T) blocked ================
// A: bf16 [MT][K] row-major per c; Wt: bf16 [N][K]; out in 8-m-blocked layout.
__global__ __launch_bounds__(256) void gemm_tn(const ushort_t* __restrict__ A,
                                               const ushort_t* __restrict__ Bt,
                                               ushort_t* __restrict__ Ob,
                                               int K, long a_cs, long b_cs, int DT){
  __shared__ __align__(16) char smem[128*136*2];
  ushort_t* As = (ushort_t*)smem;          // [128 m][32 k]
  ushort_t* Bs = As + 128*32;              // [128 n][32 k]
  ushort_t* St = (ushort_t*)smem;          // epilogue [128 n][136 m]
  int c = blockIdx.z;
  const ushort_t* Ap = A + (size_t)c*a_cs;
  const ushort_t* Bp = Bt + (size_t)c*b_cs;
  int m0 = blockIdx.y*128, n0 = blockIdx.x*128;
  int t = threadIdx.x, lane = t & 63, w = t >> 6;
  int l15 = lane & 15, quad = lane >> 4;
  int wm = (w & 1)*64, wn = (w >> 1)*64;
  f32x4 acc[4][4] = {};
  for (int k0 = 0; k0 < K; k0 += 32){
    __syncthreads();
    {
      int i = t;
      GLL16(Ap + (size_t)(m0 + (i>>2))*K + k0 + (i&3)*8, As + (size_t)(w*64)*8);
      GLL16(Bp + (size_t)(n0 + (i>>2))*K + k0 + (i&3)*8, Bs + (size_t)(w*64)*8);
      i = t + 256;
      GLL16(Ap + (size_t)(m0 + (i>>2))*K + k0 + (i&3)*8, As + (size_t)(w*64 + 256)*8);
      GLL16(Bp + (size_t)(n0 + (i>>2))*K + k0 + (i&3)*8, Bs + (size_t)(w*64 + 256)*8);
    }
    __syncthreads();
    short8 af[4], bfr[4];
    #pragma unroll
    for (int im=0; im<4; im++) af[im] = *(const short8*)(As + (size_t)(wm + im*16 + l15)*32 + quad*8);
    #pragma unroll
    for (int in=0; in<4; in++) bfr[in] = *(const short8*)(Bs + (size_t)(wn + in*16 + l15)*32 + quad*8);
    #pragma unroll
    for (int im=0; im<4; im++)
      #pragma unroll
      for (int in=0; in<4; in++)
        acc[im][in] = __builtin_amdgcn_mfma_f32_16x16x32_bf16(af[im], bfr[in], acc[im][in], 0, 0, 0);
  }
  __syncthreads();
  #pragma unroll
  for (int im=0; im<4; im++)
    #pragma unroll
    for (int in=0; in<4; in++){
      int n = wn + in*16 + l15;
      #pragma unroll
      for (int r=0; r<4; r++){
        int m = wm + im*16 + quad*4 + r;
        St[(size_t)n*136 + m] = f2b(acc[im][in][r]);
      }
    }
  __syncthreads();
  int n_loc = t >> 1, half = t & 1;
  const ushort_t* srcp = St + (size_t)n_loc*136 + half*64;
  ushort_t* dstc = Ob + (size_t)c*MT*DT;
  #pragma unroll
  for (int q=0;q<8;q++){
    size_t g = (size_t)(m0>>3) + half*8 + q;         // m-cell index (m/8)
    *(short8*)(dstc + (g*DT + n0 + n_loc)*8) = *(const short8*)(srcp + q*8);
  }
}

// ================ el/er (pre-scaled by log2e) from featB ================
template<int DH>
__global__ __launch_bounds__(256) void eler(const ushort_t* __restrict__ featB,
                                            const float* __restrict__ al, const float* __restrict__ ar,
                                            float* __restrict__ elc, float* __restrict__ erc){
  constexpr int DT = NH*DH;
  __shared__ float als[DH], ars[DH];
  int by = blockIdx.y; int c = by>>2, h = by&3;
  int t = threadIdx.x;
  int m = blockIdx.x*256 + t;
  if (t < DH){ als[t] = al[(size_t)(c*NH+h)*DH + t]; ars[t] = ar[(size_t)(c*NH+h)*DH + t]; }
  __syncthreads();
  const ushort_t* fp = featB + (((size_t)(c*512 + (m>>3))*DT + h*DH))*8 + (m&7);
  float sl = 0.f, sr = 0.f;
  #pragma unroll 8
  for (int d=0; d<DH; d++){
    float f = b2f(fp[(size_t)d*8]);
    sl += f*als[d]; sr += f*ars[d];
  }
  size_t idx = (size_t)(c*NH+h)*MT + m;
  elc[idx] = sl*LOG2E; erc[idx] = sr*LOG2E;
}

// ================ fused attention aggregation (MFMA, register P-gen) ================
// out[j,d] = (1/max(s_j,1e-9)) * sum_i p[i,j]*feat[i,d] + bias ; p = mask*2^max(s',0.2s')
// s_j via ones-column MFMA (consistent with bf16 numerator). One barrier per 64-i chunk.
// grid: 1280 1-D; group = bid%160 (XCD-shared F slice), j-tile = bid/160.
template<int DH, int RELU>
__global__ __launch_bounds__(256,4) void agg(const ushort_t* __restrict__ featB,
                                             const uint* __restrict__ adjB,
                                             const float* __restrict__ elc, const float* __restrict__ erc,
                                             const float* __restrict__ bias,
                                             ushort_t* __restrict__ outp){
  constexpr int DT = NH*DH;
  constexpr int BN = DH/16;                         // B-frags per step (8 or 4)
  __shared__ __align__(16) ushort_t Fs[2][8*DH*8];  // [buf][isub][d][8i]
  __shared__ float el_s[512];
  __shared__ uint  Ms[16*64];                       // [iw][jloc]
  int bid = blockIdx.x;
  int g = bid % 160, jt = bid / 160;
  int c = g>>5, b = (g>>2)&7, h = g&3;
  int zz = b*NC + c;
  int j0 = jt*64;
  int t = threadIdx.x, lane = t&63, w = t>>6, l15 = lane&15, quad = lane>>4;
  size_t eb = (size_t)(c*NH + h)*MT + b*NN;
  const ushort_t* fBc = featB + ((size_t)(c*512 + b*64)*DT + h*DH)*8;
  // prologue
  el_s[t] = elc[eb + t]; el_s[t+256] = elc[eb + t+256];
  #pragma unroll
  for (int k=0;k<4;k++){
    int idx = k*256 + t;
    Ms[idx] = adjB[((size_t)zz*16 + (idx>>6))*512 + j0 + (idx&63)];
  }
  float erv = erc[eb + j0 + w*16 + l15];
  short8 onesv;
  #pragma unroll
  for (int q=0;q<8;q++) onesv[q] = (short)0x3F80;
  f32x4 acc[BN] = {};
  f32x4 accs = {0.f,0.f,0.f,0.f};
  // stage chunk 0
  #pragma unroll
  for (int u=0; u<DH/32; u++){
    int gi = w*(DH/32)+u, isub = gi/(DH/64), part = gi%(DH/64);
    GLL16(fBc + (size_t)isub*DT*8 + part*512 + lane*8, &Fs[0][isub*(DH*8) + part*512]);
  }
  __syncthreads();
  for (int ic = 0; ic < 8; ic++){
    int buf = ic & 1;
    if (ic < 7){
      #pragma unroll
      for (int u=0; u<DH/32; u++){
        int gi = w*(DH/32)+u, isub = gi/(DH/64), part = gi%(DH/64);
        GLL16(fBc + (size_t)((ic+1)*8+isub)*DT*8 + part*512 + lane*8, &Fs[buf^1][isub*(DH*8) + part*512]);
      }
    }
    #pragma unroll
    for (int st=0; st<2; st++){
      int i0c = ic*64 + st*32;
      uint mby = (Ms[(i0c>>5)*64 + (w*16+l15)] >> (quad*8)) & 0xFFu;
      float4 ea = *(const float4*)&el_s[i0c + quad*8];
      float4 eb4 = *(const float4*)&el_s[i0c + quad*8 + 4];
      float ev[8] = {ea.x,ea.y,ea.z,ea.w,eb4.x,eb4.y,eb4.z,eb4.w};
      short8 af;
      #pragma unroll
      for (int q=0;q<8;q++){
        float s = ev[q] + erv;
        float lr = fmaxf(s, 0.2f*s);
        float p = EXP2F(lr);
        p = ((mby>>q)&1u) ? p : 0.f;
        af[q] = (short)f2b_fast(p);
      }
      accs = __builtin_amdgcn_mfma_f32_16x16x32_bf16(af, onesv, accs, 0, 0, 0);
      #pragma unroll
      for (int in=0; in<BN; in++){
        short8 bfr = *(const short8*)&Fs[buf][(st*4+quad)*(DH*8) + (in*16+l15)*8];
        acc[in] = __builtin_amdgcn_mfma_f32_16x16x32_bf16(af, bfr, acc[in], 0, 0, 0);
      }
    }
    __syncthreads();
  }
  // epilogue: rows jr = quad*4+r (C-layout), cols d = in*16+l15; accs has row sums
  ushort_t* op = outp + ((size_t)c*MT + b*NN + j0 + w*16)*DT + h*DH;
  float bv[BN];
  #pragma unroll
  for (int in=0; in<BN; in++) bv[in] = bias[(size_t)c*DT + h*DH + in*16 + l15];
  #pragma unroll
  for (int r=0; r<4; r++){
    int jr = quad*4 + r;
    float sinv = 1.f / fmaxf(accs[r], 1e-9f);
    #pragma unroll
    for (int in=0; in<BN; in++){
      float o = acc[in][r]*sinv + bv[in];
      if (RELU) o = fmaxf(o, 0.f);
      op[(size_t)jr*DT + in*16 + l15] = f2b_fast(o);
    }
  }
}

// ================ head mean ================
__global__ __launch_bounds__(256) void meank(const ushort_t* __restrict__ h2, float* __restrict__ outp){
  int tid = blockIdx.x*256 + threadIdx.x;
  if (tid >= MT*NC*64) return;
  int d = tid & 63; int r = tid >> 6; int c = r % NC; int m = r / NC;
  const ushort_t* p = h2 + ((size_t)c*MT + m)*256 + d;
  float s = 0.25f*(b2f(p[0]) + b2f(p[64]) + b2f(p[128]) + b2f(p[192]));
  outp[(size_t)m*(NC*64) + c*64 + d] = s;
}

extern "C" void kernel_launch(void* const* d_in, const int* in_sizes, int n_in,
                              void* d_out, int out_size, void* d_ws, size_t ws_size,
                              hipStream_t stream){
  const float* x   = (const float*)d_in[0];
  const float* adj = (const float*)d_in[1];
  const float* W0  = (const float*)d_in[2];
  const float* al0 = (const float*)d_in[3];
  const float* ar0 = (const float*)d_in[4];
  const float* b0  = (const float*)d_in[5];
  const float* W1  = (const float*)d_in[6];
  const float* al1 = (const float*)d_in[7];
  const float* ar1 = (const float*)d_in[8];
  const float* b1  = (const float*)d_in[9];
  const float* W2  = (const float*)d_in[10];
  const float* al2 = (const float*)d_in[11];
  const float* ar2 = (const float*)d_in[12];
  const float* b2  = (const float*)d_in[13];

  ushort_t* h0b  = (ushort_t*)d_ws;                 // MT*768
  ushort_t* Wt0  = h0b  + (size_t)MT*FIN;           // 5*512*768
  ushort_t* Wt1  = Wt0  + (size_t)5*512*768;        // 5*512*512
  ushort_t* Wt2  = Wt1  + (size_t)5*512*512;        // 5*256*512
  ushort_t* featB= Wt2  + (size_t)5*256*512;        // 5*MT*512 (blocked [c][m/8][d][8])
  ushort_t* hnat = featB+ (size_t)5*(size_t)MT*512; // 5*MT*512 ([c][m][DT])
  uint*     adjB = (uint*)(hnat + (size_t)5*(size_t)MT*512); // 40*16*512
  float*    elc  = (float*)(adjB + (size_t)40*16*512);
  float*    erc  = elc + (size_t)NC*NH*MT;

  prep<<<7552, 256, 0, stream>>>(x, h0b, W0, Wt0, W1, Wt1, W2, Wt2, adj, adjB);

  // layer 0
  gemm_tn<<<dim3(4,32,5), 256, 0, stream>>>(h0b, Wt0, featB, 768, 0L, (long)512*768, 512);
  eler<128><<<dim3(16,20), 256, 0, stream>>>(featB, al0, ar0, elc, erc);
  agg<128,1><<<1280, 256, 0, stream>>>(featB, adjB, elc, erc, b0, hnat);
  // layer 1
  gemm_tn<<<dim3(4,32,5), 256, 0, stream>>>(hnat, Wt1, featB, 512, (long)MT*512, (long)512*512, 512);
  eler<128><<<dim3(16,20), 256, 0, stream>>>(featB, al1, ar1, elc, erc);
  agg<128,1><<<1280, 256, 0, stream>>>(featB, adjB, elc, erc, b1, hnat);
  // layer 2 (no relu)
  gemm_tn<<<dim3(2,32,5), 256, 0, stream>>>(hnat, Wt2, featB, 512, (long)MT*512, (long)256*512, 256);
  eler<64><<<dim3(16,20), 256, 0, stream>>>(featB, al2, ar2, elc, erc);
  agg<64,0><<<1280, 256, 0, stream>>>(featB, adjB, elc, erc, b2, hnat);

  meank<<<5120, 256, 0, stream>>>(hnat, (float*)d_out);
}

// Round 5
// 303.705 us; speedup vs baseline: 3.8440x; 1.0352x over previous
//
#include <hip/hip_runtime.h>

typedef unsigned int uint;
typedef unsigned short ushort_t;
typedef __attribute__((ext_vector_type(8))) short short8;
typedef __attribute__((ext_vector_type(4))) float f32x4;

#define NB 8
#define NC 5
#define NN 512
#define FIN 768
#define NH 4
#define MT 4096   // NB*NN rows, m = b*512+n

__device__ __forceinline__ float b2f(ushort_t u){ uint x = ((uint)u)<<16; return __builtin_bit_cast(float, x); }
__device__ __forceinline__ ushort_t f2b(float f){
  uint u = __builtin_bit_cast(uint, f);
  u += 0x7FFFu + ((u>>16)&1u);
  return (ushort_t)(u>>16);
}
__device__ __forceinline__ ushort_t f2b_fast(float f){
  uint u = __builtin_bit_cast(uint, f);
  return (ushort_t)((u + 0x8000u)>>16);
}

// async global->LDS, 16B/lane; lds base wave-uniform (HW adds lane*16)
#define GLL16(gp, lp) __builtin_amdgcn_global_load_lds( \
    (const __attribute__((address_space(1))) void*)(gp), \
    (__attribute__((address_space(3))) void*)(lp), 16, 0, 0)

// ================ fused prep: conv_h0 | wtrans x3 | adjacency bitpack ================
__global__ __launch_bounds__(256) void prep(const float* __restrict__ x, ushort_t* __restrict__ h0b,
                                            const float* __restrict__ W0, ushort_t* __restrict__ Wt0,
                                            const float* __restrict__ W1, ushort_t* __restrict__ Wt1,
                                            const float* __restrict__ W2, ushort_t* __restrict__ Wt2,
                                            const float* __restrict__ adj, uint* __restrict__ adjB){
  __shared__ float tile[32][33];
  int bid = blockIdx.x, t = threadIdx.x;
  if (bid < 3072){
    int tid = bid*256 + t;                    // over MT*192
    int row = tid/192, q = tid%192;
    int b = row >> 9, n = row & 511;
    float4 v = *(const float4*)(x + ((size_t)(b*NC)*NN + n)*FIN + q*4);
    ushort4 o; o.x = f2b(v.x); o.y = f2b(v.y); o.z = f2b(v.z); o.w = f2b(v.w);
    *(ushort4*)(h0b + (size_t)row*FIN + q*4) = o;
  } else if (bid < 6912){
    const float* W; ushort_t* Wt; int K, N, c, x0, y0;
    if (bid < 4992){ int l = bid-3072; K=768; N=512; W=W0; Wt=Wt0; c=l/384; int r=l%384; x0=r%16; y0=r/16; }
    else if (bid < 6272){ int l = bid-4992; K=512; N=512; W=W1; Wt=Wt1; c=l/256; int r=l%256; x0=r%16; y0=r/16; }
    else { int l = bid-6272; K=512; N=256; W=W2; Wt=Wt2; c=l/128; int r=l%128; x0=r%8; y0=r/8; }
    int n0 = x0*32, k0 = y0*32;
    int tx = t & 31, ty = t >> 5;
    const float* Wp = W + (size_t)c*K*N;
    ushort_t* Wtp = Wt + (size_t)c*K*N;
    #pragma unroll
    for (int r=0;r<4;r++) tile[ty+r*8][tx] = Wp[(size_t)(k0+ty+r*8)*N + n0+tx];
    __syncthreads();
    #pragma unroll
    for (int r=0;r<4;r++) Wtp[(size_t)(n0+ty+r*8)*K + k0+tx] = f2b(tile[tx][ty+r*8]);
  } else {
    int l = bid - 6912;                       // 640: zz*16 + iw
    int iw = l & 15, zz = l >> 4;
    const float* ap = adj + (size_t)zz*NN*NN + (size_t)iw*32*NN;
    uint w0 = 0, w1 = 0;
    #pragma unroll 8
    for (int q=0;q<32;q++){
      if (ap[(size_t)q*NN + t]       > 0.f) w0 |= (1u<<q);
      if (ap[(size_t)q*NN + t + 256] > 0.f) w1 |= (1u<<q);
    }
    adjB[((size_t)zz*16 + iw)*512 + t]       = w0;
    adjB[((size_t)zz*16 + iw)*512 + t + 256] = w1;
  }
}

// ================ MFMA GEMM + fused el/er/exp-table epilogue ================
// featB[c][m/8][n][8] = (A @ Wt^T); each n-tile (128) covers whole head(s), so the
// block computes el/er for its 128 m rows directly from the St tile in LDS.
template<int DH>
__global__ __launch_bounds__(256) void gemm_tn(const ushort_t* __restrict__ A,
                                               const ushort_t* __restrict__ Bt,
                                               ushort_t* __restrict__ Ob,
                                               const float* __restrict__ al, const float* __restrict__ ar,
                                               float* __restrict__ el, float* __restrict__ E1, float* __restrict__ E2,
                                               float* __restrict__ er, float* __restrict__ R1, float* __restrict__ R2,
                                               int K, long a_cs, long b_cs){
  constexpr int DT = NH*DH;
  __shared__ __align__(16) char smem[128*136*2];
  __shared__ float als_s[128], ars_s[128];
  ushort_t* As = (ushort_t*)smem;          // [128 m][32 k]
  ushort_t* Bs = As + 128*32;              // [128 n][32 k]
  ushort_t* St = (ushort_t*)smem;          // epilogue [128 n][136 m]
  int c = blockIdx.z;
  const ushort_t* Ap = A + (size_t)c*a_cs;
  const ushort_t* Bp = Bt + (size_t)c*b_cs;
  int m0 = blockIdx.y*128, n0 = blockIdx.x*128;
  int t = threadIdx.x, lane = t & 63, w = t >> 6;
  int l15 = lane & 15, quad = lane >> 4;
  int wm = (w & 1)*64, wn = (w >> 1)*64;
  if (t < 128){
    als_s[t] = al[(size_t)c*NH*DH + n0 + t];   // (H,D) flattened == local n
    ars_s[t] = ar[(size_t)c*NH*DH + n0 + t];
  }
  f32x4 acc[4][4] = {};
  for (int k0 = 0; k0 < K; k0 += 32){
    __syncthreads();
    {
      int i = t;
      GLL16(Ap + (size_t)(m0 + (i>>2))*K + k0 + (i&3)*8, As + (size_t)(w*64)*8);
      GLL16(Bp + (size_t)(n0 + (i>>2))*K + k0 + (i&3)*8, Bs + (size_t)(w*64)*8);
      i = t + 256;
      GLL16(Ap + (size_t)(m0 + (i>>2))*K + k0 + (i&3)*8, As + (size_t)(w*64 + 256)*8);
      GLL16(Bp + (size_t)(n0 + (i>>2))*K + k0 + (i&3)*8, Bs + (size_t)(w*64 + 256)*8);
    }
    __syncthreads();
    short8 af[4], bfr[4];
    #pragma unroll
    for (int im=0; im<4; im++) af[im] = *(const short8*)(As + (size_t)(wm + im*16 + l15)*32 + quad*8);
    #pragma unroll
    for (int in=0; in<4; in++) bfr[in] = *(const short8*)(Bs + (size_t)(wn + in*16 + l15)*32 + quad*8);
    #pragma unroll
    for (int im=0; im<4; im++)
      #pragma unroll
      for (int in=0; in<4; in++)
        acc[im][in] = __builtin_amdgcn_mfma_f32_16x16x32_bf16(af[im], bfr[in], acc[im][in], 0, 0, 0);
  }
  __syncthreads();
  #pragma unroll
  for (int im=0; im<4; im++)
    #pragma unroll
    for (int in=0; in<4; in++){
      int n = wn + in*16 + l15;
      #pragma unroll
      for (int r=0; r<4; r++){
        int m = wm + im*16 + quad*4 + r;
        St[(size_t)n*136 + m] = f2b(acc[im][in][r]);
      }
    }
  __syncthreads();
  // blocked store
  {
    int n_loc = t >> 1, half = t & 1;
    const ushort_t* srcp = St + (size_t)n_loc*136 + half*64;
    ushort_t* dstc = Ob + (size_t)c*MT*DT;
    #pragma unroll
    for (int q=0;q<8;q++){
      size_t g = (size_t)(m0>>3) + half*8 + q;       // m-cell index (m/8)
      *(short8*)(dstc + (g*DT + n0 + n_loc)*8) = *(const short8*)(srcp + q*8);
    }
  }
  // fused el/er + exp tables
  {
    int m = t >> 1, half = t & 1;
    float sl = 0.f, sr = 0.f;
    const ushort_t* stp = St + (size_t)(half*64)*136 + m;
    #pragma unroll 8
    for (int nn=0; nn<64; nn++){
      float f = b2f(stp[(size_t)nn*136]);
      int n = half*64 + nn;
      sl += f*als_s[n]; sr += f*ars_s[n];
    }
    size_t base = (size_t)c*NH*MT;
    if (DH == 128){
      sl += __shfl_xor(sl, 1); sr += __shfl_xor(sr, 1);
      size_t idx = base + (size_t)(n0>>7)*MT + m0 + m;
      if (half == 0){ el[idx]=sl; E1[idx]=__expf(sl); E2[idx]=__expf(0.2f*sl); }
      else          { er[idx]=sr; R1[idx]=__expf(sr); R2[idx]=__expf(0.2f*sr); }
    } else {
      size_t idx = base + (size_t)((n0>>6)+half)*MT + m0 + m;
      el[idx]=sl; E1[idx]=__expf(sl); E2[idx]=__expf(0.2f*sl);
      er[idx]=sr; R1[idx]=__expf(sr); R2[idx]=__expf(0.2f*sr);
    }
  }
}

// ================ fused attention aggregation (MFMA, register P-gen, exp-table) ================
// out[j,d] = (1/max(s_j,1e-9)) * sum_i p[i,j]*feat[i,d] + bias
// p = mask * ((el_i+er_j>0) ? E1_i*R1_j : E2_i*R2_j) ; s_j via ones-column MFMA.
// grid: 1280 1-D; group = bid%160 (XCD-shared F slice), j-tile = bid/160.
template<int DH, int RELU>
__global__ __launch_bounds__(256,4) void agg(const ushort_t* __restrict__ featB,
                                             const uint* __restrict__ adjB,
                                             const float* __restrict__ el, const float* __restrict__ E1,
                                             const float* __restrict__ E2,
                                             const float* __restrict__ er, const float* __restrict__ R1,
                                             const float* __restrict__ R2,
                                             const float* __restrict__ bias,
                                             ushort_t* __restrict__ outp){
  constexpr int DT = NH*DH;
  constexpr int BN = DH/16;                         // B-frags per step (8 or 4)
  __shared__ __align__(16) ushort_t Fs[2][8*DH*8];  // [buf][isub][d][8i]
  __shared__ float el_s[512], E1_s[512], E2_s[512];
  int bid = blockIdx.x;
  int g = bid % 160, jt = bid / 160;
  int c = g>>5, b = (g>>2)&7, h = g&3;
  int zz = b*NC + c;
  int j0 = jt*64;
  int t = threadIdx.x, lane = t&63, w = t>>6, l15 = lane&15, quad = lane>>4;
  size_t eb = (size_t)(c*NH + h)*MT + b*NN;
  const ushort_t* fBc = featB + ((size_t)(c*512 + b*64)*DT + h*DH)*8;
  // prologue: per-node tables into LDS; mask words + per-j scalars into VGPRs
  el_s[t] = el[eb + t]; el_s[t+256] = el[eb + t+256];
  E1_s[t] = E1[eb + t]; E1_s[t+256] = E1[eb + t+256];
  E2_s[t] = E2[eb + t]; E2_s[t+256] = E2[eb + t+256];
  int jme = j0 + w*16 + l15;                        // this lane's j (A-operand row)
  float erv = er[eb + jme];
  float R1v = R1[eb + jme];
  float R2v = R2[eb + jme];
  uint mw[16];
  #pragma unroll
  for (int iw=0; iw<16; iw++) mw[iw] = adjB[((size_t)zz*16 + iw)*512 + jme];
  short8 onesv;
  #pragma unroll
  for (int q=0;q<8;q++) onesv[q] = (short)0x3F80;
  f32x4 acc[BN] = {};
  f32x4 accs = {0.f,0.f,0.f,0.f};
  // stage chunk 0
  #pragma unroll
  for (int u=0; u<DH/32; u++){
    int gi = w*(DH/32)+u, isub = gi/(DH/64), part = gi%(DH/64);
    GLL16(fBc + (size_t)isub*DT*8 + part*512 + lane*8, &Fs[0][isub*(DH*8) + part*512]);
  }
  __syncthreads();
  for (int ic = 0; ic < 8; ic++){
    int buf = ic & 1;
    if (ic < 7){
      #pragma unroll
      for (int u=0; u<DH/32; u++){
        int gi = w*(DH/32)+u, isub = gi/(DH/64), part = gi%(DH/64);
        GLL16(fBc + (size_t)((ic+1)*8+isub)*DT*8 + part*512 + lane*8, &Fs[buf^1][isub*(DH*8) + part*512]);
      }
    }
    #pragma unroll
    for (int st=0; st<2; st++){
      int i0c = ic*64 + st*32;
      uint mby = (mw[i0c>>5] >> (quad*8)) & 0xFFu;
      float4 ea  = *(const float4*)&el_s[i0c + quad*8];
      float4 eb4 = *(const float4*)&el_s[i0c + quad*8 + 4];
      float4 x1a = *(const float4*)&E1_s[i0c + quad*8];
      float4 x1b = *(const float4*)&E1_s[i0c + quad*8 + 4];
      float4 x2a = *(const float4*)&E2_s[i0c + quad*8];
      float4 x2b = *(const float4*)&E2_s[i0c + quad*8 + 4];
      float ev[8]  = {ea.x,ea.y,ea.z,ea.w,eb4.x,eb4.y,eb4.z,eb4.w};
      float e1v[8] = {x1a.x,x1a.y,x1a.z,x1a.w,x1b.x,x1b.y,x1b.z,x1b.w};
      float e2v[8] = {x2a.x,x2a.y,x2a.z,x2a.w,x2b.x,x2b.y,x2b.z,x2b.w};
      short8 af;
      #pragma unroll
      for (int q=0;q<8;q++){
        float s = ev[q] + erv;
        float p = (s > 0.f) ? (e1v[q]*R1v) : (e2v[q]*R2v);
        p = ((mby>>q)&1u) ? p : 0.f;
        af[q] = (short)f2b_fast(p);
      }
      accs = __builtin_amdgcn_mfma_f32_16x16x32_bf16(af, onesv, accs, 0, 0, 0);
      #pragma unroll
      for (int in=0; in<BN; in++){
        short8 bfr = *(const short8*)&Fs[buf][(st*4+quad)*(DH*8) + (in*16+l15)*8];
        acc[in] = __builtin_amdgcn_mfma_f32_16x16x32_bf16(af, bfr, acc[in], 0, 0, 0);
      }
    }
    __syncthreads();
  }
  // epilogue: rows jr = quad*4+r (C-layout), cols d = in*16+l15; accs has row sums
  ushort_t* op = outp + ((size_t)c*MT + b*NN + j0 + w*16)*DT + h*DH;
  float bv[BN];
  #pragma unroll
  for (int in=0; in<BN; in++) bv[in] = bias[(size_t)c*DT + h*DH + in*16 + l15];
  #pragma unroll
  for (int r=0; r<4; r++){
    int jr = quad*4 + r;
    float sinv = 1.f / fmaxf(accs[r], 1e-9f);
    #pragma unroll
    for (int in=0; in<BN; in++){
      float o = acc[in][r]*sinv + bv[in];
      if (RELU) o = fmaxf(o, 0.f);
      op[(size_t)jr*DT + in*16 + l15] = f2b_fast(o);
    }
  }
}

// ================ head mean ================
__global__ __launch_bounds__(256) void meank(const ushort_t* __restrict__ h2, float* __restrict__ outp){
  int tid = blockIdx.x*256 + threadIdx.x;
  if (tid >= MT*NC*64) return;
  int d = tid & 63; int r = tid >> 6; int c = r % NC; int m = r / NC;
  const ushort_t* p = h2 + ((size_t)c*MT + m)*256 + d;
  float s = 0.25f*(b2f(p[0]) + b2f(p[64]) + b2f(p[128]) + b2f(p[192]));
  outp[(size_t)m*(NC*64) + c*64 + d] = s;
}

extern "C" void kernel_launch(void* const* d_in, const int* in_sizes, int n_in,
                              void* d_out, int out_size, void* d_ws, size_t ws_size,
                              hipStream_t stream){
  const float* x   = (const float*)d_in[0];
  const float* adj = (const float*)d_in[1];
  const float* W0  = (const float*)d_in[2];
  const float* al0 = (const float*)d_in[3];
  const float* ar0 = (const float*)d_in[4];
  const float* b0  = (const float*)d_in[5];
  const float* W1  = (const float*)d_in[6];
  const float* al1 = (const float*)d_in[7];
  const float* ar1 = (const float*)d_in[8];
  const float* b1  = (const float*)d_in[9];
  const float* W2  = (const float*)d_in[10];
  const float* al2 = (const float*)d_in[11];
  const float* ar2 = (const float*)d_in[12];
  const float* b2  = (const float*)d_in[13];

  ushort_t* h0b  = (ushort_t*)d_ws;                 // MT*768
  ushort_t* Wt0  = h0b  + (size_t)MT*FIN;           // 5*512*768
  ushort_t* Wt1  = Wt0  + (size_t)5*512*768;        // 5*512*512
  ushort_t* Wt2  = Wt1  + (size_t)5*512*512;        // 5*256*512
  ushort_t* featB= Wt2  + (size_t)5*256*512;        // 5*MT*512 (blocked [c][m/8][d][8])
  ushort_t* hnat = featB+ (size_t)5*(size_t)MT*512; // 5*MT*512 ([c][m][DT])
  uint*     adjB = (uint*)(hnat + (size_t)5*(size_t)MT*512); // 40*16*512
  float*    elp  = (float*)(adjB + (size_t)40*16*512);       // 6 x NC*NH*MT fp32
  float*    E1p  = elp + (size_t)NC*NH*MT;
  float*    E2p  = E1p + (size_t)NC*NH*MT;
  float*    erp  = E2p + (size_t)NC*NH*MT;
  float*    R1p  = erp + (size_t)NC*NH*MT;
  float*    R2p  = R1p + (size_t)NC*NH*MT;

  prep<<<7552, 256, 0, stream>>>(x, h0b, W0, Wt0, W1, Wt1, W2, Wt2, adj, adjB);

  // layer 0
  gemm_tn<128><<<dim3(4,32,5), 256, 0, stream>>>(h0b, Wt0, featB, al0, ar0,
                                                 elp, E1p, E2p, erp, R1p, R2p,
                                                 768, 0L, (long)512*768);
  agg<128,1><<<1280, 256, 0, stream>>>(featB, adjB, elp, E1p, E2p, erp, R1p, R2p, b0, hnat);
  // layer 1
  gemm_tn<128><<<dim3(4,32,5), 256, 0, stream>>>(hnat, Wt1, featB, al1, ar1,
                                                 elp, E1p, E2p, erp, R1p, R2p,
                                                 512, (long)MT*512, (long)512*512);
  agg<128,1><<<1280, 256, 0, stream>>>(featB, adjB, elp, E1p, E2p, erp, R1p, R2p, b1, hnat);
  // layer 2 (no relu)
  gemm_tn<64><<<dim3(2,32,5), 256, 0, stream>>>(hnat, Wt2, featB, al2, ar2,
                                                elp, E1p, E2p, erp, R1p, R2p,
                                                512, (long)MT*512, (long)256*512);
  agg<64,0><<<1280, 256, 0, stream>>>(featB, adjB, elp, E1p, E2p, erp, R1p, R2p, b2, hnat);

  meank<<<5120, 256, 0, stream>>>(hnat, (float*)d_out);
}